// Round 15
// baseline (426.069 us; speedup 1.0000x reference)
//
#include <hip/hip_runtime.h>
#include <math.h>

#define N_TOK 131072
#define DIM   64
#define QS    8
#define KS    1024

typedef _Float16 f16x8 __attribute__((ext_vector_type(8)));
typedef float    f32x4 __attribute__((ext_vector_type(4)));

#define RSCALE   2048.0f
#define RISCALE  4.8828125e-4f   // 2^-11

// split fp32 v into f16 limbs + scaled-hi: v ~= hi + lo*2^-11 ; hs = 2048*hi (exact)
#define SPLIT3(v, hi, lo, hs) { _Float16 _h = (_Float16)(v); (hi) = _h;        \
                                (lo) = (_Float16)(((v) - (float)_h) * RSCALE); \
                                (hs) = (_Float16)((float)_h * RSCALE); }

// ---- workspace layout G: 128 chunks, each 16640 B:
//   [0    .. 16383]  frag limbs: 16 sub-slots of 1KB (4 groups x {h0,h1,l0,l1})
//   [16384.. 16639]  64 floats: -1024*||c||^2 seeds for the chunk's 64 codewords
// Chunk c covers stage q = c>>4, codewords (c&15)*64 .. +63.

// ---- pre-pass 1: codebook -> f16 limbs in MFMA fragment order.
// slot = (q*64+g)*4 + l*2 + h ; chunk c = slot>>4, sub = slot&15.
__global__ void conv_kernel(const float* __restrict__ cb, _Float16* __restrict__ G) {
    int t = blockIdx.x * blockDim.x + threadIdx.x;
    if (t >= 2048 * 64) return;
    const int lane = t & 63, slot = t >> 6;
    const int h = slot & 1, l = (slot >> 1) & 1, g = (slot >> 2) & 63, q = slot >> 8;
    const int cw = g * 16 + (lane & 15);
    const int d0 = h * 32 + (lane >> 4) * 8;
    const float* src = cb + ((size_t)q * KS + cw) * DIM + d0;
    f16x8 v;
#pragma unroll
    for (int j = 0; j < 8; ++j) {
        float c = src[j];
        _Float16 hi = (_Float16)c;
        v[j] = (l == 0) ? hi : (_Float16)((c - (float)hi) * RSCALE);
    }
    const int c = slot >> 4, w = slot & 15;
    *(f16x8*)(G + (size_t)c * 8320 + w * 512 + lane * 8) = v;
}

// ---- pre-pass 2: dc2 seeds written straight into each chunk's tail ----
__global__ void dc2_kernel(const float* __restrict__ cb, float* __restrict__ Gf) {
    int i = blockIdx.x * blockDim.x + threadIdx.x;
    if (i < QS * KS) {
        const float* c = cb + (size_t)i * DIM;
        float s = 0.f;
#pragma unroll
        for (int d = 0; d < DIM; ++d) s = fmaf(c[d], c[d], s);
        const int q = i >> 10, k = i & 1023;
        const int ch = q * 16 + (k >> 6), j = k & 63;
        Gf[(size_t)ch * 4160 + 4096 + j] = -1024.0f * s;
    }
}

#define CHUNK_B   16640     // bytes per chunk (16KB frags + 256B dc2)
#define CHUNK_H   8320      // _Float16 elements per chunk
#define DC2_OFF_H 8192      // half-offset of dc2 region (byte 16384)

// ---- main: r14 structure (4 token-sets/wave, pair-intervals, deferred argmin)
// with group PAIRS fused into one interleaved 48-MFMA cluster: 8 INDEPENDENT
// depth-6 chains (4 sets x 2 groups) issued round-robin. Rationale: the
// 380us plateau fits chain-starvation -- 4 chains/wave x 2 waves = 8
// chains/SIMD covering only ~50% of the ~310cyc dependent-MFMA latency at
// one issue per 19.4cyc. 8 chains/wave -> 16/SIMD ~= full coverage.
// Per-chain FP order unchanged (ts0,ts1,th0,th1,tl0,tl1) -> bit-identical.
__global__ __launch_bounds__(256, 2)
void rvq_mfma_kernel(const float* __restrict__ x,
                     const float* __restrict__ cbf,
                     const _Float16* __restrict__ F,
                     float* __restrict__ out) {
    extern __shared__ _Float16 smem[];   // 2 buffers x 2 chunks x CHUNK_H = 66560 B

    const int tid  = threadIdx.x;
    const int wave = tid >> 6;
    const int lane = tid & 63;
    const int quad = lane >> 4;
    const int m    = lane & 15;
    const int quad4 = quad * 4;

    const int tokenBase = blockIdx.x * 256 + wave * 64;

    // token limbs, 4 sets (B-frag layout): th = hi, tl = 2048*(r-hi), ts = 2048*hi
    f16x8 th00, th01, tl00, tl01, ts00, ts01;
    f16x8 th10, th11, tl10, tl11, ts10, ts11;
    f16x8 th20, th21, tl20, tl21, ts20, ts21;
    f16x8 th30, th31, tl30, tl31, ts30, ts31;

#define LOADTOK(S, TH0, TH1, TL0, TL1, TS0, TS1) {                                \
        const float* xa = x + (size_t)(tokenBase + (S) * 16 + m) * DIM + quad * 8;\
        f32x4 a0 = __builtin_nontemporal_load((const f32x4*)(xa));                \
        f32x4 a1 = __builtin_nontemporal_load((const f32x4*)(xa + 4));            \
        f32x4 a2 = __builtin_nontemporal_load((const f32x4*)(xa + 32));           \
        f32x4 a3 = __builtin_nontemporal_load((const f32x4*)(xa + 36));           \
        _Pragma("unroll")                                                         \
        for (int j = 0; j < 4; ++j) {                                             \
            SPLIT3(a0[j], TH0[j],   TL0[j],   TS0[j]);                            \
            SPLIT3(a1[j], TH0[j+4], TL0[j+4], TS0[j+4]);                          \
            SPLIT3(a2[j], TH1[j],   TL1[j],   TS1[j]);                            \
            SPLIT3(a3[j], TH1[j+4], TL1[j+4], TS1[j+4]);                          \
        }                                                                         \
    }
    LOADTOK(0, th00, th01, tl00, tl01, ts00, ts01);
    LOADTOK(1, th10, th11, tl10, tl11, ts10, ts11);
    LOADTOK(2, th20, th21, tl20, tl21, ts20, ts21);
    LOADTOK(3, th30, th31, tl30, tl31, ts30, ts31);

// stage chunk GC into pair-buffer BUF, slot J (0/1).
#define STAGE(GC, BUF, J) {                                                       \
        const char* _gs = (const char*)F + (size_t)(GC) * CHUNK_B                 \
                          + (wave << 10) + (lane << 4);                           \
        _Float16* _ld = smem + (BUF) * (2 * CHUNK_H) + (J) * CHUNK_H              \
                        + (wave << 9);                                            \
        _Pragma("unroll")                                                         \
        for (int _j = 0; _j < 4; ++_j)                                            \
            __builtin_amdgcn_global_load_lds(                                     \
                (const __attribute__((address_space(1))) void*)(_gs + _j * 4096), \
                (__attribute__((address_space(3))) void*)(_ld + _j * 2048),       \
                16, 0, 0);                                                        \
        if (wave == 0) {                                                          \
            const char* _gd = (const char*)F + (size_t)(GC) * CHUNK_B + 16384     \
                              + (lane << 2);                                      \
            __builtin_amdgcn_global_load_lds(                                     \
                (const __attribute__((address_space(1))) void*)_gd,               \
                (__attribute__((address_space(3))) void*)(smem                    \
                    + (BUF) * (2 * CHUNK_H) + (J) * CHUNK_H + DC2_OFF_H),         \
                4, 0, 0);                                                         \
        }                                                                         \
    }

#define MF(D, CA, TB, CC) D = __builtin_amdgcn_mfma_f32_16x16x32_f16(CA, TB, CC, 0,0,0)

// 48 MFMAs: 8 INDEPENDENT depth-6 chains (4 sets x groups {A,B}), issued
// round-robin across chains per chain-step. Per-chain op order identical to
// the old MFMA24 (ts h0, ts h1, th l0, th l1, tl h0, tl h1) -> bit-identical.
#define MFMA48(H0A, H1A, L0A, L1A, H0B, H1B, L0B, L1B, CIA, CIB,                    \
               A0, A1, A2, A3, B0, B1, B2, B3) {                                    \
        MF(A0, H0A, ts00, CIA); MF(B0, H0B, ts00, CIB);                             \
        MF(A1, H0A, ts10, CIA); MF(B1, H0B, ts10, CIB);                             \
        MF(A2, H0A, ts20, CIA); MF(B2, H0B, ts20, CIB);                             \
        MF(A3, H0A, ts30, CIA); MF(B3, H0B, ts30, CIB);                             \
        MF(A0, H1A, ts01, A0);  MF(B0, H1B, ts01, B0);                              \
        MF(A1, H1A, ts11, A1);  MF(B1, H1B, ts11, B1);                              \
        MF(A2, H1A, ts21, A2);  MF(B2, H1B, ts21, B2);                              \
        MF(A3, H1A, ts31, A3);  MF(B3, H1B, ts31, B3);                              \
        MF(A0, L0A, th00, A0);  MF(B0, L0B, th00, B0);                              \
        MF(A1, L0A, th10, A1);  MF(B1, L0B, th10, B1);                              \
        MF(A2, L0A, th20, A2);  MF(B2, L0B, th20, B2);                              \
        MF(A3, L0A, th30, A3);  MF(B3, L0B, th30, B3);                              \
        MF(A0, L1A, th01, A0);  MF(B0, L1B, th01, B0);                              \
        MF(A1, L1A, th11, A1);  MF(B1, L1B, th11, B1);                              \
        MF(A2, L1A, th21, A2);  MF(B2, L1B, th21, B2);                              \
        MF(A3, L1A, th31, A3);  MF(B3, L1B, th31, B3);                              \
        MF(A0, H0A, tl00, A0);  MF(B0, H0B, tl00, B0);                              \
        MF(A1, H0A, tl10, A1);  MF(B1, H0B, tl10, B1);                              \
        MF(A2, H0A, tl20, A2);  MF(B2, H0B, tl20, B2);                              \
        MF(A3, H0A, tl30, A3);  MF(B3, H0B, tl30, B3);                              \
        MF(A0, H1A, tl01, A0);  MF(B0, H1B, tl01, B0);                              \
        MF(A1, H1A, tl11, A1);  MF(B1, H1B, tl11, B1);                              \
        MF(A2, H1A, tl21, A2);  MF(B2, H1B, tl21, B2);                              \
        MF(A3, H1A, tl31, A3);  MF(B3, H1B, tl31, B3);                              \
    }

// argmin scan of one group's accs (4 sets x 4 elems, ascending -> tie-break ok)
#define ARGMIN(A0, A1, A2, A3, G) {                                                \
        const int base = (G) * 16 + quad4;                                         \
        _Pragma("unroll")                                                          \
        for (int i = 0; i < 4; ++i) {                                              \
            if (A0[i] > bv0) { bv0 = A0[i]; bi0 = base + i; }                      \
            if (A1[i] > bv1) { bv1 = A1[i]; bi1 = base + i; }                      \
            if (A2[i] > bv2) { bv2 = A2[i]; bi2 = base + i; }                      \
            if (A3[i] > bv3) { bv3 = A3[i]; bi3 = base + i; }                      \
        }                                                                          \
    }

// one chunk's compute: groups fused in pairs; argmin of pair 0 deferred past
// pair 1's MFMA issue (compare-VALU fills pair 1's pipe-latency window).
#define CHUNKBODY(LBASE, GBASE) {                                                 \
        const _Float16* L   = (LBASE) + lane * 8;                                 \
        const float*    dcL = (const float*)((LBASE) + DC2_OFF_H);                \
        f32x4 ci0 = *(const f32x4*)(dcL +  0 + quad4);                            \
        f32x4 ci1 = *(const f32x4*)(dcL + 16 + quad4);                            \
        f32x4 ci2 = *(const f32x4*)(dcL + 32 + quad4);                            \
        f32x4 ci3 = *(const f32x4*)(dcL + 48 + quad4);                            \
        f16x8 g0h0 = *(const f16x8*)(L);                                          \
        f16x8 g0h1 = *(const f16x8*)(L + 512);                                    \
        f16x8 g0l0 = *(const f16x8*)(L + 1024);                                   \
        f16x8 g0l1 = *(const f16x8*)(L + 1536);                                   \
        f16x8 g1h0 = *(const f16x8*)(L + 2048);                                   \
        f16x8 g1h1 = *(const f16x8*)(L + 2560);                                   \
        f16x8 g1l0 = *(const f16x8*)(L + 3072);                                   \
        f16x8 g1l1 = *(const f16x8*)(L + 3584);                                   \
        f32x4 pA0, pA1, pA2, pA3, pB0, pB1, pB2, pB3;                             \
        f32x4 pC0, pC1, pC2, pC3, pD0, pD1, pD2, pD3;                             \
        MFMA48(g0h0, g0h1, g0l0, g0l1, g1h0, g1h1, g1l0, g1l1, ci0, ci1,          \
               pA0, pA1, pA2, pA3, pB0, pB1, pB2, pB3);                           \
        f16x8 g2h0 = *(const f16x8*)(L + 4096);                                   \
        f16x8 g2h1 = *(const f16x8*)(L + 4608);                                   \
        f16x8 g2l0 = *(const f16x8*)(L + 5120);                                   \
        f16x8 g2l1 = *(const f16x8*)(L + 5632);                                   \
        f16x8 g3h0 = *(const f16x8*)(L + 6144);                                   \
        f16x8 g3h1 = *(const f16x8*)(L + 6656);                                   \
        f16x8 g3l0 = *(const f16x8*)(L + 7168);                                   \
        f16x8 g3l1 = *(const f16x8*)(L + 7680);                                   \
        MFMA48(g2h0, g2h1, g2l0, g2l1, g3h0, g3h1, g3l0, g3l1, ci2, ci3,          \
               pC0, pC1, pC2, pC3, pD0, pD1, pD2, pD3);                           \
        ARGMIN(pA0, pA1, pA2, pA3, (GBASE) + 0);                                  \
        ARGMIN(pB0, pB1, pB2, pB3, (GBASE) + 1);                                  \
        ARGMIN(pC0, pC1, pC2, pC3, (GBASE) + 2);                                  \
        ARGMIN(pD0, pD1, pD2, pD3, (GBASE) + 3);                                  \
    }

    // prologue: stage pair 0 (chunks 0,1) into buffer 0
    STAGE(0, 0, 0);
    STAGE(1, 0, 1);
    __syncthreads();
    int cur = 0;

    for (int q = 0; q < QS; ++q) {
        const float* cfq = cbf + (size_t)q * KS * DIM;

        float bv0 = -INFINITY, bv1 = -INFINITY, bv2 = -INFINITY, bv3 = -INFINITY;
        int   bi0 = 0, bi1 = 0, bi2 = 0, bi3 = 0;

        for (int p = 0; p < 8; ++p) {
            const int gp = (q << 3) | p;            // global pair 0..63
            if (gp + 1 < 64) {                      // prefetch next pair
                STAGE(2 * gp + 2, cur ^ 1, 0);
                STAGE(2 * gp + 3, cur ^ 1, 1);
            }

            _Float16* base = smem + cur * (2 * CHUNK_H);
            CHUNKBODY(base,           (p * 2 + 0) * 4);
            CHUNKBODY(base + CHUNK_H, (p * 2 + 1) * 4);

            // barrier (with implicit vmcnt/lgkm drain): staged pair gp+1
            // resident; all waves done reading buffer cur.
            __syncthreads();
            cur ^= 1;
        }

        // reduce over the 4 quad-lanes holding the same token (disjoint codewords):
        // 2 shuffle steps. Tie-break: lowest index, matching jnp.argmin.
#define REDUCE(BV, BI) {                                                          \
        _Pragma("unroll")                                                         \
        for (int mask = 16; mask <= 32; mask <<= 1) {                             \
            float ov = __shfl_xor(BV, mask, 64);                                  \
            int   oi = __shfl_xor(BI, mask, 64);                                  \
            if (ov > BV || (ov == BV && oi < BI)) { BV = ov; BI = oi; }           \
        }                                                                         \
    }
        REDUCE(bv0, bi0); REDUCE(bv1, bi1); REDUCE(bv2, bi2); REDUCE(bv3, bi3);

        // index writes: quad s writes set s's token (64 lanes = 64 tokens)
        {
            const int myTok = tokenBase + quad * 16 + m;
            const int mybi  = (quad == 0) ? bi0 : (quad == 1) ? bi1
                            : (quad == 2) ? bi2 : bi3;
            out[(size_t)N_TOK * DIM + (size_t)myTok * QS + q] = (float)mybi;
        }

        // residual update per set: reconstruct r, subtract fp32 codeword, re-split
        float ls = 0.f;
#define RESID(BI, TH0, TH1, TL0, TL1, TS0, TS1) {                                 \
        const float* cp = cfq + (size_t)(BI) * DIM + quad * 8;                    \
        f32x4 c0 = *(const f32x4*)(cp);                                           \
        f32x4 c1 = *(const f32x4*)(cp + 4);                                       \
        f32x4 c2 = *(const f32x4*)(cp + 32);                                      \
        f32x4 c3 = *(const f32x4*)(cp + 36);                                      \
        _Pragma("unroll")                                                         \
        for (int j = 0; j < 4; ++j) {                                             \
            float v0 = fmaf(RISCALE, (float)TL0[j],   (float)TH0[j])   - c0[j];   \
            float v1 = fmaf(RISCALE, (float)TL0[j+4], (float)TH0[j+4]) - c1[j];   \
            float v2 = fmaf(RISCALE, (float)TL1[j],   (float)TH1[j])   - c2[j];   \
            float v3 = fmaf(RISCALE, (float)TL1[j+4], (float)TH1[j+4]) - c3[j];   \
            ls = fmaf(v0, v0, ls); ls = fmaf(v1, v1, ls);                         \
            ls = fmaf(v2, v2, ls); ls = fmaf(v3, v3, ls);                         \
            SPLIT3(v0, TH0[j],   TL0[j],   TS0[j]);                               \
            SPLIT3(v1, TH0[j+4], TL0[j+4], TS0[j+4]);                             \
            SPLIT3(v2, TH1[j],   TL1[j],   TS1[j]);                               \
            SPLIT3(v3, TH1[j+4], TL1[j+4], TS1[j+4]);                             \
        }                                                                         \
    }
        RESID(bi0, th00, th01, tl00, tl01, ts00, ts01);
        RESID(bi1, th10, th11, tl10, tl11, ts10, ts11);
        RESID(bi2, th20, th21, tl20, tl21, ts20, ts21);
        RESID(bi3, th30, th31, tl30, tl31, ts30, ts31);

#pragma unroll
        for (int mask = 1; mask <= 32; mask <<= 1) ls += __shfl_xor(ls, mask, 64);
        if (lane == 0)
            atomicAdd(out + (size_t)N_TOK * DIM + (size_t)N_TOK * QS + q,
                      ls * (1.0f / ((float)N_TOK * (float)DIM)));
    }

    // xq = x - r_final (reconstruct final residual from limbs), per set
#define XQW(S, TH0, TH1, TL0, TL1) {                                              \
        const size_t ra = (size_t)(tokenBase + (S) * 16 + m) * DIM + quad * 8;    \
        f32x4 a0 = __builtin_nontemporal_load((const f32x4*)(x + ra));            \
        f32x4 a1 = __builtin_nontemporal_load((const f32x4*)(x + ra + 4));        \
        f32x4 a2 = __builtin_nontemporal_load((const f32x4*)(x + ra + 32));       \
        f32x4 a3 = __builtin_nontemporal_load((const f32x4*)(x + ra + 36));       \
        _Pragma("unroll")                                                         \
        for (int j = 0; j < 4; ++j) {                                             \
            a0[j] -= fmaf(RISCALE, (float)TL0[j],   (float)TH0[j]);               \
            a1[j] -= fmaf(RISCALE, (float)TL0[j+4], (float)TH0[j+4]);             \
            a2[j] -= fmaf(RISCALE, (float)TL1[j],   (float)TH1[j]);               \
            a3[j] -= fmaf(RISCALE, (float)TL1[j+4], (float)TH1[j+4]);             \
        }                                                                         \
        __builtin_nontemporal_store(a0, (f32x4*)(out + ra));                      \
        __builtin_nontemporal_store(a1, (f32x4*)(out + ra + 4));                  \
        __builtin_nontemporal_store(a2, (f32x4*)(out + ra + 32));                 \
        __builtin_nontemporal_store(a3, (f32x4*)(out + ra + 36));                 \
    }
    XQW(0, th00, th01, tl00, tl01);
    XQW(1, th10, th11, tl10, tl11);
    XQW(2, th20, th21, tl20, tl21);
    XQW(3, th30, th31, tl30, tl31);

#undef MF
#undef MFMA48
#undef ARGMIN
#undef CHUNKBODY
#undef STAGE
#undef LOADTOK
#undef REDUCE
#undef RESID
#undef XQW
}

extern "C" void kernel_launch(void* const* d_in, const int* in_sizes, int n_in,
                              void* d_out, int out_size, void* d_ws, size_t ws_size,
                              hipStream_t stream) {
    const float* x   = (const float*)d_in[0];   // (N, D)
    const float* cb  = (const float*)d_in[1];   // (Q, K, D)
    float*       out = (float*)d_out;           // [xq | indices | losses]
    char*        ws  = (char*)d_ws;

    _Float16* G = (_Float16*)ws;   // 128 chunks x 16640 B = 2,129,920 B

    hipMemsetAsync(out + (size_t)N_TOK * DIM + (size_t)N_TOK * QS, 0,
                   QS * sizeof(float), stream);

    conv_kernel<<<512, 256, 0, stream>>>(cb, G);
    dc2_kernel<<<(QS * KS + 255) / 256, 256, 0, stream>>>(cb, (float*)ws);
    rvq_mfma_kernel<<<N_TOK / 256, 256, 4 * CHUNK_H * sizeof(_Float16), stream>>>(
        x, cb, G, out);
}